// Round 1
// baseline (282.991 us; speedup 1.0000x reference)
//
#include <hip/hip_runtime.h>
#include <hip/hip_bf16.h>

typedef __hip_bfloat16 bf16;

#define B_  16
#define H_  64
#define N_  64
#define L_  16384
#define LC_ 64
#define NCH_ 256

// ---------------- K0: per-(h,n) tables -------------------------------------
// rtab[h][n][2]   = r = exp(dt*A)
// rLtab[h][n][2]  = r^64
// Ptab[h][n][j][2]= 2*Ck*r^(j+1), j=0..63
// Ktab[h][d]      = 2*Re(sum_n Ck*r^d), d=0..63
__global__ void k0_setup(const float* __restrict__ log_dt, const float* __restrict__ C_ri,
                         const float* __restrict__ log_A_real, const float* __restrict__ A_imag,
                         float* __restrict__ rtab, float* __restrict__ rLtab,
                         float* __restrict__ Ptab, float* __restrict__ Ktab)
{
    __shared__ float arr[64][65];
    int h = blockIdx.x, n = threadIdx.x;
    int hn = h * 64 + n;
    float dt  = expf(log_dt[h]);
    float Are = -expf(log_A_real[hn]);
    float Aim = A_imag[hn];
    float er  = expf(Are * dt);
    float rre = er * cosf(Aim * dt);
    float rim = er * sinf(Aim * dt);
    float Cre = C_ri[2 * hn], Cim = C_ri[2 * hn + 1];
    // Ck = C * (r-1)/A  (A = Are + i*Aim)
    float emre = rre - 1.f, emim = rim;
    float inva2 = 1.f / (Are * Are + Aim * Aim);
    float qre = (emre * Are + emim * Aim) * inva2;
    float qim = (emim * Are - emre * Aim) * inva2;
    float ckre = Cre * qre - Cim * qim;
    float ckim = Cre * qim + Cim * qre;
    rtab[2 * hn] = rre; rtab[2 * hn + 1] = rim;
    arr[0][n] = 2.f * ckre;                       // K[0] partial: 2Re(Ck)
    float pre = rre, pim = rim;                   // p = r^(j+1)
    for (int j = 0; j < 64; ++j) {
        float wre = 2.f * (ckre * pre - ckim * pim);
        float wim = 2.f * (ckre * pim + ckim * pre);
        Ptab[(size_t)hn * 128 + 2 * j]     = wre;
        Ptab[(size_t)hn * 128 + 2 * j + 1] = wim;
        if (j < 63) {
            arr[j + 1][n] = wre;                  // K[j+1] partial: 2Re(Ck r^(j+1))
            float t = pre * rre - pim * rim;
            pim = pre * rim + pim * rre;
            pre = t;
        }
    }
    rLtab[2 * hn] = pre; rLtab[2 * hn + 1] = pim; // r^64
    __syncthreads();
    float s = 0.f;
    for (int k = 0; k < 64; ++k) s += arr[n][k];  // thread n sums K[d=n]
    Ktab[h * 64 + n] = s;
}

// ---------------- K1: per-chunk end-state contribs -------------------------
// contrib[bh][n][ri][c] (bf16), c = chunk index 0..255; thread = chunk
__global__ __launch_bounds__(256) void k1_contrib(const float* __restrict__ u,
        const int* __restrict__ length, const float* __restrict__ rtab,
        bf16* __restrict__ contrib)
{
    int bh = blockIdx.x;
    int b = bh >> 6, h = bh & 63;
    int c = threadIdx.x;
    int len = length[b];
    int l0 = c * LC_;
    const float* up = u + (size_t)bh * L_ + l0;
    float x[64];
    #pragma unroll
    for (int k = 0; k < 16; ++k) {
        float4 v = *(const float4*)(up + 4 * k);
        x[4 * k + 0] = (l0 + 4 * k + 0 < len) ? v.x : 0.f;
        x[4 * k + 1] = (l0 + 4 * k + 1 < len) ? v.y : 0.f;
        x[4 * k + 2] = (l0 + 4 * k + 2 < len) ? v.z : 0.f;
        x[4 * k + 3] = (l0 + 4 * k + 3 < len) ? v.w : 0.f;
    }
    const float* rp = rtab + h * 128;
    bf16* cp = contrib + (size_t)bh * 32768 + c;
    for (int n = 0; n < 64; ++n) {
        float rre = rp[2 * n], rim = rp[2 * n + 1];
        float sre = 0.f, sim = 0.f;
        #pragma unroll
        for (int t = 0; t < 64; ++t) {            // s = r*s + x[t]
            float tre = fmaf(rre, sre, fmaf(-rim, sim, x[t]));
            sim = fmaf(rre, sim, rim * sre);
            sre = tre;
        }
        cp[n * 512]       = __float2bfloat16(sre);
        cp[n * 512 + 256] = __float2bfloat16(sim);
    }
}

// ---------------- K2: scan carries across chunks (in place) ----------------
// thread g = (b*64+h)*64+n ; carry[c] = state before chunk c
__global__ __launch_bounds__(256) void k2_scan(const float* __restrict__ rLtab,
                                               bf16* __restrict__ buf)
{
    int g = blockIdx.x * 256 + threadIdx.x;
    int n = g & 63;
    int h = (g >> 6) & 63;
    float rre = rLtab[2 * (h * 64 + n)], rim = rLtab[2 * (h * 64 + n) + 1];
    bf16* p = buf + (size_t)g * 512;
    float sre = 0.f, sim = 0.f;
    for (int c2 = 0; c2 < 256; ++c2) {
        float tre = __bfloat162float(p[c2]);
        float tim = __bfloat162float(p[c2 + 256]);
        p[c2]       = __float2bfloat16(sre);
        p[c2 + 256] = __float2bfloat16(sim);
        float nre = fmaf(rre, sre, fmaf(-rim, sim, tre));
        sim = fmaf(rre, sim, fmaf(rim, sre, tim));
        sre = nre;
    }
}

// ---------------- K3: corr + local conv + D*u + mask + stats ---------------
__global__ __launch_bounds__(256, 2) void k3_main(const float* __restrict__ u,
        const int* __restrict__ length, const float* __restrict__ Dp,
        const bf16* __restrict__ carry, const float* __restrict__ Ptab,
        const float* __restrict__ Ktab, bf16* __restrict__ y, double* __restrict__ stats)
{
    __shared__ float plds[8192];   // P[h]: [n][j][2]  (32 KB)
    __shared__ float klds[64];
    int bh = blockIdx.x;
    int b = bh >> 6, h = bh & 63;
    int tid = threadIdx.x;
    {
        const float4* ps = (const float4*)(Ptab + (size_t)h * 8192);
        float4* pd = (float4*)plds;
        for (int i = tid; i < 2048; i += 256) pd[i] = ps[i];
        if (tid < 64) klds[tid] = Ktab[h * 64 + tid];
    }
    __syncthreads();
    float yacc[64];
    #pragma unroll
    for (int j = 0; j < 64; ++j) yacc[j] = 0.f;
    // ---- carry correction: yacc[j] += sum_n (PR*cre - PI*cim)
    const bf16* cb = carry + (size_t)bh * 32768 + tid;
    for (int n = 0; n < 64; ++n) {
        float cre = __bfloat162float(cb[n * 512]);
        float cim = __bfloat162float(cb[n * 512 + 256]);
        const float4* pp = (const float4*)(plds + n * 128);
        #pragma unroll
        for (int j2 = 0; j2 < 32; ++j2) {
            float4 q = pp[j2];
            yacc[2 * j2]     = fmaf(q.x, cre, fmaf(-q.y, cim, yacc[2 * j2]));
            yacc[2 * j2 + 1] = fmaf(q.z, cre, fmaf(-q.w, cim, yacc[2 * j2 + 1]));
        }
    }
    // ---- local triangular convolution within the chunk
    int len = length[b];
    int l0 = tid * 64;
    const float* up = u + (size_t)bh * L_ + l0;
    float x[64];
    #pragma unroll
    for (int k = 0; k < 16; ++k) {
        float4 v = *(const float4*)(up + 4 * k);
        x[4 * k + 0] = (l0 + 4 * k + 0 < len) ? v.x : 0.f;
        x[4 * k + 1] = (l0 + 4 * k + 1 < len) ? v.y : 0.f;
        x[4 * k + 2] = (l0 + 4 * k + 2 < len) ? v.z : 0.f;
        x[4 * k + 3] = (l0 + 4 * k + 3 < len) ? v.w : 0.f;
    }
    float kv[64];
    #pragma unroll
    for (int d = 0; d < 64; ++d) kv[d] = klds[d];
    #pragma unroll
    for (int t = 0; t < 64; ++t) {
        #pragma unroll
        for (int j = t; j < 64; ++j)
            yacc[j] = fmaf(kv[j - t], x[t], yacc[j]);
    }
    // ---- + D*um, mask, store, stats
    float Dh = Dp[h];
    double s = 0.0, ss = 0.0;
    bf16* yp = y + (size_t)bh * L_ + l0;
    #pragma unroll
    for (int j = 0; j < 64; ++j) {
        float v = fmaf(Dh, x[j], yacc[j]);
        v = (l0 + j < len) ? v : 0.f;
        yp[j] = __float2bfloat16(v);
        s += (double)v;
        ss = fma((double)v, (double)v, ss);
    }
    #pragma unroll
    for (int off = 32; off > 0; off >>= 1) {
        s  += __shfl_down(s, off, 64);
        ss += __shfl_down(ss, off, 64);
    }
    if ((tid & 63) == 0) {
        atomicAdd(&stats[2 * h],     s);
        atomicAdd(&stats[2 * h + 1], ss);
    }
}

// ---------------- K4: layernorm + FiLM + tanh + residual -------------------
__global__ __launch_bounds__(256) void k4_final(const float* __restrict__ u,
        const bf16* __restrict__ y, const float* __restrict__ cond,
        const float* __restrict__ fw, const float* __restrict__ fb,
        const double* __restrict__ stats, float* __restrict__ out)
{
    int idx = blockIdx.x * 256 + threadIdx.x;
    int bh = idx >> 14;
    int b = bh >> 6, h = bh & 63;
    __shared__ float gg[2];
    if (threadIdx.x == 0) {
        float g = fb[h], bb = fb[64 + h];
        #pragma unroll
        for (int k = 0; k < 3; ++k) {
            g  = fmaf(cond[b * 3 + k], fw[h * 3 + k], g);
            bb = fmaf(cond[b * 3 + k], fw[(64 + h) * 3 + k], bb);
        }
        gg[0] = g; gg[1] = bb;
    }
    __syncthreads();
    double inv = 1.0 / (16.0 * 16384.0);
    double mean_d = stats[2 * h] * inv;
    double var_d  = stats[2 * h + 1] * inv - mean_d * mean_d;
    float mean = (float)mean_d;
    float rstd = rsqrtf((float)var_d + 1e-5f);
    float yv = __bfloat162float(y[idx]);
    float z = fmaf((yv - mean) * rstd, gg[0], gg[1]);
    out[idx] = u[idx] + tanhf(z);
}

// ---------------------------------------------------------------------------
extern "C" void kernel_launch(void* const* d_in, const int* in_sizes, int n_in,
                              void* d_out, int out_size, void* d_ws, size_t ws_size,
                              hipStream_t stream)
{
    const float* u           = (const float*)d_in[0];
    const float* cond        = (const float*)d_in[1];
    const int*   length      = (const int*)  d_in[2];
    const float* log_dt      = (const float*)d_in[3];
    const float* C_ri        = (const float*)d_in[4];
    const float* log_A_real  = (const float*)d_in[5];
    const float* A_imag      = (const float*)d_in[6];
    const float* D           = (const float*)d_in[7];
    const float* film_w      = (const float*)d_in[8];
    const float* film_b      = (const float*)d_in[9];
    float* out = (float*)d_out;

    char* w = (char*)d_ws;
    bf16*   y       = (bf16*)w;                       // 33,554,432 B
    bf16*   contrib = (bf16*)(w + 33554432);          // 67,108,864 B
    float*  Ptab    = (float*)(w + 100663296);        //  2,097,152 B
    float*  rtab    = (float*)(w + 102760448);        //     32,768 B
    float*  rLtab   = (float*)(w + 102793216);        //     32,768 B
    float*  Ktab    = (float*)(w + 102825984);        //     16,384 B
    double* stats   = (double*)(w + 102842368);       //      1,024 B  (total ~98.1 MB)

    hipMemsetAsync(stats, 0, 1024, stream);
    hipLaunchKernelGGL(k0_setup,  dim3(64),    dim3(64),  0, stream,
                       log_dt, C_ri, log_A_real, A_imag, rtab, rLtab, Ptab, Ktab);
    hipLaunchKernelGGL(k1_contrib, dim3(1024), dim3(256), 0, stream, u, length, rtab, contrib);
    hipLaunchKernelGGL(k2_scan,    dim3(256),  dim3(256), 0, stream, rLtab, contrib);
    hipLaunchKernelGGL(k3_main,    dim3(1024), dim3(256), 0, stream,
                       u, length, D, contrib, Ptab, Ktab, y, stats);
    hipLaunchKernelGGL(k4_final,   dim3(65536), dim3(256), 0, stream,
                       u, y, cond, film_w, film_b, stats, out);
}

// Round 4
// 143.377 us; speedup vs baseline: 1.9738x; 1.9738x over previous
//
#include <hip/hip_runtime.h>
#include <hip/hip_bf16.h>

typedef __hip_bfloat16 bf16;
typedef __attribute__((ext_vector_type(8))) short s16x8;
typedef __attribute__((ext_vector_type(4))) float f32x4;

#define SWZ(c) (((c) & 7) << 4)

__device__ __forceinline__ unsigned short f2b(float x){
    __hip_bfloat16 h = __float2bfloat16(x);
    return __builtin_bit_cast(unsigned short, h);
}
__device__ __forceinline__ float b2f(unsigned short s){
    unsigned int u = (unsigned int)s << 16;
    return __builtin_bit_cast(float, u);
}

// ---------------- K0: per-h split-bf16 MFMA tables -------------------------
// Qh/Ql[h][n2=128][t=64] : Q[2n][t]=Re r^{63-t}, Q[2n+1][t]=Im r^{63-t}
// Pmh/Pml[h][j=64][n2=128]: Pm[j][2n]=Re(2Ck r^{j+1}), [2n+1]=-Im(...)
// Klh/Kll[h][j=64][t=64] : Kd[j-t] for t<=j else 0
// rLtab[h][n][2] = r^64 ; rL2tab[h][n][2] = r^4096   (f32, for the scan)
__global__ __launch_bounds__(64) void k0_setup(const float* __restrict__ log_dt,
        const float* __restrict__ C_ri, const float* __restrict__ log_A_real,
        const float* __restrict__ A_imag, float* __restrict__ rLtab,
        float* __restrict__ rL2tab,
        short* __restrict__ Qh, short* __restrict__ Ql,
        short* __restrict__ Pmh, short* __restrict__ Pml,
        short* __restrict__ Klh, short* __restrict__ Kll)
{
    __shared__ float arr[64][65];
    __shared__ float kd[64];
    int h = blockIdx.x, n = threadIdx.x;
    int hn = h * 64 + n;
    float dt  = expf(log_dt[h]);
    float Are = -expf(log_A_real[hn]);
    float Aim = A_imag[hn];
    float er  = expf(Are * dt);
    float rre = er * cosf(Aim * dt);
    float rim = er * sinf(Aim * dt);
    float Cre = C_ri[2 * hn], Cim = C_ri[2 * hn + 1];
    float emre = rre - 1.f, emim = rim;
    float inva2 = 1.f / (Are * Are + Aim * Aim);
    float qre_ = (emre * Are + emim * Aim) * inva2;
    float qim_ = (emim * Are - emre * Aim) * inva2;
    float ckre = Cre * qre_ - Cim * qim_;
    float ckim = Cre * qim_ + Cim * qre_;
    {   // Q rows 2n, 2n+1 ; p = r^{63-t}
        float pre = 1.f, pim = 0.f;
        short* qh0 = Qh + (size_t)h * 8192 + (2 * n) * 64;
        short* qh1 = qh0 + 64;
        short* ql0 = Ql + (size_t)h * 8192 + (2 * n) * 64;
        short* ql1 = ql0 + 64;
        for (int t = 63; t >= 0; --t) {
            unsigned short h0 = f2b(pre), h1 = f2b(pim);
            qh0[t] = (short)h0; ql0[t] = (short)f2b(pre - b2f(h0));
            qh1[t] = (short)h1; ql1[t] = (short)f2b(pim - b2f(h1));
            float tr = pre * rre - pim * rim;
            pim = pre * rim + pim * rre;
            pre = tr;
        }
        rLtab[2 * hn] = pre; rLtab[2 * hn + 1] = pim;     // r^64
        float p2re = pre, p2im = pim;                      // r^4096 = (r^64)^64
        for (int i = 0; i < 6; ++i) {
            float t2 = p2re * p2re - p2im * p2im;
            p2im = 2.f * p2re * p2im;
            p2re = t2;
        }
        rL2tab[2 * hn] = p2re; rL2tab[2 * hn + 1] = p2im;
    }
    arr[0][n] = 2.f * ckre;                               // Kd[0] partial
    {   // Pm columns 2n, 2n+1 across j ; p = r^{j+1}
        float pre = rre, pim = rim;
        short* pmh = Pmh + (size_t)h * 8192;
        short* pml = Pml + (size_t)h * 8192;
        for (int j = 0; j < 64; ++j) {
            float wre = 2.f * (ckre * pre - ckim * pim);
            float wim = 2.f * (ckre * pim + ckim * pre);
            unsigned short h0 = f2b(wre), h1 = f2b(-wim);
            pmh[j * 128 + 2 * n]     = (short)h0;
            pml[j * 128 + 2 * n]     = (short)f2b(wre - b2f(h0));
            pmh[j * 128 + 2 * n + 1] = (short)h1;
            pml[j * 128 + 2 * n + 1] = (short)f2b(-wim - b2f(h1));
            if (j < 63) arr[j + 1][n] = wre;              // Kd[j+1] partial
            float tr = pre * rre - pim * rim;
            pim = pre * rim + pim * rre;
            pre = tr;
        }
    }
    __syncthreads();
    float s = 0.f;
    for (int k2 = 0; k2 < 64; ++k2) s += arr[n][k2];
    kd[n] = s;
    __syncthreads();
    short* klh = Klh + (size_t)h * 4096 + n * 64;         // Klow row j=n
    short* kll = Kll + (size_t)h * 4096 + n * 64;
    for (int t = 0; t < 64; ++t) {
        if (t <= n) {
            float v = kd[n - t];
            unsigned short h0 = f2b(v);
            klh[t] = (short)h0;
            kll[t] = (short)f2b(v - b2f(h0));
        } else { klh[t] = 0; kll[t] = 0; }
    }
}

// ---------------- fused: conv(GEMM) + per-half [S(GEMM)->scan->corr(GEMM)] --
// block = (b,h); 4 waves; wave w owns c-rows [64w, 64w+64)
__global__ __launch_bounds__(256, 2) void k_fused(const float* __restrict__ u,
        const int* __restrict__ length, const float* __restrict__ Dp,
        const float* __restrict__ rLtab, const float* __restrict__ rL2tab,
        const short* __restrict__ Qh, const short* __restrict__ Ql,
        const short* __restrict__ Pmh, const short* __restrict__ Pml,
        const short* __restrict__ Klh, const short* __restrict__ Kll,
        bf16* __restrict__ y, double* __restrict__ stats)
{
    __shared__ __align__(16) unsigned char lds[65536];  // S_half f32 [c=256][n2f=64] (256B rows)
    int bh = blockIdx.x;
    int b = bh >> 6, h = bh & 63;
    int tid = threadIdx.x;
    int w = tid >> 6, lane = tid & 63;
    int lo = lane & 15, hi = lane >> 4;
    int len = length[b];
    const float* ub = u + (size_t)bh * 16384;

    // ---- phase 0: X fragments in registers, hi+lo split (masked u)
    s16x8 xh[4][2], xl[4][2];
    #pragma unroll
    for (int ct = 0; ct < 4; ++ct) {
        int c = w * 64 + ct * 16 + lo;
        #pragma unroll
        for (int kt = 0; kt < 2; ++kt) {
            int gidx = c * 64 + kt * 32 + hi * 8;
            float4 v0 = *(const float4*)(ub + gidx);
            float4 v1 = *(const float4*)(ub + gidx + 4);
            float xv[8] = {v0.x, v0.y, v0.z, v0.w, v1.x, v1.y, v1.z, v1.w};
            s16x8 fh, fl;
            #pragma unroll
            for (int e = 0; e < 8; ++e) {
                float xm = (gidx + e < len) ? xv[e] : 0.f;
                unsigned short h0 = f2b(xm);
                fh[e] = (short)h0;
                fl[e] = (short)f2b(xm - b2f(h0));
            }
            xh[ct][kt] = fh;
            xl[ct][kt] = fl;
        }
    }

    // ---- phase 1: local conv  Y[c][j] += sum_t X[c][t]*Klow[t][j]
    f32x4 acc[4][4];
    #pragma unroll
    for (int ct = 0; ct < 4; ++ct)
        #pragma unroll
        for (int jt = 0; jt < 4; ++jt)
            acc[ct][jt] = f32x4{0.f, 0.f, 0.f, 0.f};
    {
        const short* klhb = Klh + (size_t)h * 4096;
        const short* kllb = Kll + (size_t)h * 4096;
        #pragma unroll
        for (int kt = 0; kt < 2; ++kt) {
            #pragma unroll
            for (int jt = 0; jt < 4; ++jt) {
                s16x8 kfh = *(const s16x8*)(klhb + (jt * 16 + lo) * 64 + kt * 32 + hi * 8);
                s16x8 kfl = *(const s16x8*)(kllb + (jt * 16 + lo) * 64 + kt * 32 + hi * 8);
                #pragma unroll
                for (int ct = 0; ct < 4; ++ct) {
                    acc[ct][jt] = __builtin_amdgcn_mfma_f32_16x16x32_bf16(xh[ct][kt], kfh, acc[ct][jt], 0, 0, 0);
                    acc[ct][jt] = __builtin_amdgcn_mfma_f32_16x16x32_bf16(xh[ct][kt], kfl, acc[ct][jt], 0, 0, 0);
                    acc[ct][jt] = __builtin_amdgcn_mfma_f32_16x16x32_bf16(xl[ct][kt], kfh, acc[ct][jt], 0, 0, 0);
                }
            }
        }
    }

    // ---- two n2-halves: GEMM1 (S f32) -> scan (split-bf16 carry) -> GEMM3
    for (int half = 0; half < 2; ++half) {
        // GEMM1-half: S[n2f][c], n2f = mt'*16+4hi+rg, write f32x4 per D-frag
        {
            const short* qhb = Qh + (size_t)h * 8192 + half * 64 * 64;
            const short* qlb = Ql + (size_t)h * 8192 + half * 64 * 64;
            #pragma unroll
            for (int mt = 0; mt < 4; ++mt) {
                s16x8 qh0 = *(const s16x8*)(qhb + (mt * 16 + lo) * 64 + hi * 8);
                s16x8 qh1 = *(const s16x8*)(qhb + (mt * 16 + lo) * 64 + 32 + hi * 8);
                s16x8 ql0 = *(const s16x8*)(qlb + (mt * 16 + lo) * 64 + hi * 8);
                s16x8 ql1 = *(const s16x8*)(qlb + (mt * 16 + lo) * 64 + 32 + hi * 8);
                #pragma unroll
                for (int ct = 0; ct < 4; ++ct) {
                    f32x4 sacc = f32x4{0.f, 0.f, 0.f, 0.f};
                    sacc = __builtin_amdgcn_mfma_f32_16x16x32_bf16(qh0, xh[ct][0], sacc, 0, 0, 0);
                    sacc = __builtin_amdgcn_mfma_f32_16x16x32_bf16(qh1, xh[ct][1], sacc, 0, 0, 0);
                    sacc = __builtin_amdgcn_mfma_f32_16x16x32_bf16(ql0, xh[ct][0], sacc, 0, 0, 0);
                    sacc = __builtin_amdgcn_mfma_f32_16x16x32_bf16(ql1, xh[ct][1], sacc, 0, 0, 0);
                    sacc = __builtin_amdgcn_mfma_f32_16x16x32_bf16(qh0, xl[ct][0], sacc, 0, 0, 0);
                    sacc = __builtin_amdgcn_mfma_f32_16x16x32_bf16(qh1, xl[ct][1], sacc, 0, 0, 0);
                    int c = w * 64 + ct * 16 + lo;
                    *(f32x4*)(lds + c * 256 + ((64 * mt + 16 * hi) ^ SWZ(c))) = sacc;
                }
            }
        }
        __syncthreads();

        // scan-half: 128 threads; mode m=tid>>2 (of 32), segment s=tid&3 (64 chunks)
        if (tid < 128) {
            int m = tid >> 2, s = tid & 3;
            int gm = h * 64 + half * 32 + m;
            float r64re = rLtab[2 * gm],  r64im = rLtab[2 * gm + 1];
            float r4kre = rL2tab[2 * gm], r4kim = rL2tab[2 * gm + 1];
            // pass 1: segment end-state
            float ere = 0.f, eim = 0.f;
            for (int i = 0; i < 64; ++i) {
                int c = 64 * s + i;
                float2 v = *(const float2*)(lds + c * 256 + ((8 * m) ^ SWZ(c)));
                float nre = fmaf(r64re, ere, fmaf(-r64im, eim, v.x));
                eim = fmaf(r64re, eim, fmaf(r64im, ere, v.y));
                ere = nre;
            }
            // combine: exclusive prefix over segments (4-lane group = one mode)
            int base = tid & ~3;
            float cire = 0.f, ciim = 0.f;
            #pragma unroll
            for (int k = 0; k < 3; ++k) {
                float Ere = __shfl(ere, base + k, 64);
                float Eim = __shfl(eim, base + k, 64);
                if (k < s) {
                    float nre = fmaf(r4kre, cire, fmaf(-r4kim, ciim, Ere));
                    ciim = fmaf(r4kre, ciim, fmaf(r4kim, cire, Eim));
                    cire = nre;
                }
            }
            // pass 2: write split-bf16 carries (packed per 4-mode group), advance
            int g = m >> 2, k4 = m & 3;
            int hib = 32 * g + 4 * k4, lob = 32 * g + 16 + 4 * k4;
            for (int i = 0; i < 64; ++i) {
                int c = 64 * s + i;
                float2 v = *(const float2*)(lds + c * 256 + ((8 * m) ^ SWZ(c)));
                unsigned short hre = f2b(cire), him = f2b(ciim);
                unsigned short lre = f2b(cire - b2f(hre)), lim = f2b(ciim - b2f(him));
                *(unsigned int*)(lds + c * 256 + (hib ^ SWZ(c))) = (unsigned)hre | ((unsigned)him << 16);
                *(unsigned int*)(lds + c * 256 + (lob ^ SWZ(c))) = (unsigned)lre | ((unsigned)lim << 16);
                float nre = fmaf(r64re, cire, fmaf(-r64im, ciim, v.x));
                ciim = fmaf(r64re, ciim, fmaf(r64im, cire, v.y));
                cire = nre;
            }
        }
        __syncthreads();

        // GEMM3-half: Y[c][j] += sum_{n2f} carry[c][n2f] * Pm[n2 global][j]
        {
            const short* pmhb = Pmh + (size_t)h * 8192 + half * 64;
            const short* pmlb = Pml + (size_t)h * 8192 + half * 64;
            #pragma unroll
            for (int kt2 = 0; kt2 < 2; ++kt2) {
                s16x8 ah[4], al[4];
                #pragma unroll
                for (int ct = 0; ct < 4; ++ct) {
                    int c = w * 64 + ct * 16 + lo;
                    int G = kt2 * 4 + hi;
                    ah[ct] = *(const s16x8*)(lds + c * 256 + ((32 * G) ^ SWZ(c)));
                    al[ct] = *(const s16x8*)(lds + c * 256 + ((32 * G + 16) ^ SWZ(c)));
                }
                #pragma unroll
                for (int jt = 0; jt < 4; ++jt) {
                    s16x8 pfh = *(const s16x8*)(pmhb + (jt * 16 + lo) * 128 + kt2 * 32 + hi * 8);
                    s16x8 pfl = *(const s16x8*)(pmlb + (jt * 16 + lo) * 128 + kt2 * 32 + hi * 8);
                    #pragma unroll
                    for (int ct = 0; ct < 4; ++ct) {
                        acc[ct][jt] = __builtin_amdgcn_mfma_f32_16x16x32_bf16(ah[ct], pfh, acc[ct][jt], 0, 0, 0);
                        acc[ct][jt] = __builtin_amdgcn_mfma_f32_16x16x32_bf16(ah[ct], pfl, acc[ct][jt], 0, 0, 0);
                        acc[ct][jt] = __builtin_amdgcn_mfma_f32_16x16x32_bf16(al[ct], pfh, acc[ct][jt], 0, 0, 0);
                    }
                }
            }
        }
        __syncthreads();
    }

    // ---- Y staging: acc f32 -> lds [c=256][j=64] f32 (256B rows)
    #pragma unroll
    for (int ct = 0; ct < 4; ++ct) {
        #pragma unroll
        for (int jt = 0; jt < 4; ++jt) {
            int j = jt * 16 + lo;
            #pragma unroll
            for (int rg = 0; rg < 4; ++rg) {
                int c = w * 64 + ct * 16 + hi * 4 + rg;
                *(float*)(lds + c * 256 + ((j * 4) ^ SWZ(c))) = acc[ct][jt][rg];
            }
        }
    }
    __syncthreads();

    // ---- epilogue: + D*u, mask, single-rounded y store, double stats
    float Dh = Dp[h];
    double s1 = 0.0, s2 = 0.0;
    short* yg = (short*)y + (size_t)bh * 16384;
    #pragma unroll
    for (int k = 0; k < 8; ++k) {
        int eidx = (k * 256 + tid) * 8;
        int row = eidx >> 6;
        int colb = (eidx & 63) * 4;
        f32x4 ya = *(const f32x4*)(lds + row * 256 + (colb ^ SWZ(row)));
        f32x4 yb = *(const f32x4*)(lds + row * 256 + ((colb + 16) ^ SWZ(row)));
        float4 u0 = *(const float4*)(ub + eidx);
        float4 u1 = *(const float4*)(ub + eidx + 4);
        float uv[8] = {u0.x, u0.y, u0.z, u0.w, u1.x, u1.y, u1.z, u1.w};
        float yv[8] = {ya[0], ya[1], ya[2], ya[3], yb[0], yb[1], yb[2], yb[3]};
        s16x8 o;
        #pragma unroll
        for (int e = 0; e < 8; ++e) {
            float vv = fmaf(Dh, uv[e], yv[e]);
            vv = (eidx + e < len) ? vv : 0.f;
            o[e] = (short)f2b(vv);
            s1 += (double)vv;
            s2 = fma((double)vv, (double)vv, s2);
        }
        *(s16x8*)(yg + eidx) = o;
    }
    #pragma unroll
    for (int off = 32; off > 0; off >>= 1) {
        s1 += __shfl_down(s1, off, 64);
        s2 += __shfl_down(s2, off, 64);
    }
    if (lane == 0) {
        atomicAdd(&stats[2 * h],     s1);
        atomicAdd(&stats[2 * h + 1], s2);
    }
}

// ---------------- K4: layernorm + FiLM + tanh + residual -------------------
__global__ __launch_bounds__(256) void k4_final(const float* __restrict__ u,
        const bf16* __restrict__ y, const float* __restrict__ cond,
        const float* __restrict__ fw, const float* __restrict__ fb,
        const double* __restrict__ stats, float* __restrict__ out)
{
    int idx = blockIdx.x * 256 + threadIdx.x;
    int bh = idx >> 14;
    int b = bh >> 6, h = bh & 63;
    __shared__ float gg[2];
    if (threadIdx.x == 0) {
        float g = fb[h], bb = fb[64 + h];
        #pragma unroll
        for (int k = 0; k < 3; ++k) {
            g  = fmaf(cond[b * 3 + k], fw[h * 3 + k], g);
            bb = fmaf(cond[b * 3 + k], fw[(64 + h) * 3 + k], bb);
        }
        gg[0] = g; gg[1] = bb;
    }
    __syncthreads();
    double inv = 1.0 / (16.0 * 16384.0);
    double mean_d = stats[2 * h] * inv;
    double var_d  = stats[2 * h + 1] * inv - mean_d * mean_d;
    float mean = (float)mean_d;
    float rstd = rsqrtf((float)var_d + 1e-5f);
    float yv = __bfloat162float(y[idx]);
    float z = fmaf((yv - mean) * rstd, gg[0], gg[1]);
    out[idx] = u[idx] + tanhf(z);
}

// ---------------------------------------------------------------------------
extern "C" void kernel_launch(void* const* d_in, const int* in_sizes, int n_in,
                              void* d_out, int out_size, void* d_ws, size_t ws_size,
                              hipStream_t stream)
{
    const float* u           = (const float*)d_in[0];
    const float* cond        = (const float*)d_in[1];
    const int*   length      = (const int*)  d_in[2];
    const float* log_dt      = (const float*)d_in[3];
    const float* C_ri        = (const float*)d_in[4];
    const float* log_A_real  = (const float*)d_in[5];
    const float* A_imag      = (const float*)d_in[6];
    const float* D           = (const float*)d_in[7];
    const float* film_w      = (const float*)d_in[8];
    const float* film_b      = (const float*)d_in[9];
    float* out = (float*)d_out;

    char* w = (char*)d_ws;
    bf16*   y      = (bf16*)w;                    // 33,554,432 B
    short*  Qh     = (short*)(w + 33554432);      //  1,048,576 B
    short*  Ql     = (short*)(w + 34603008);      //  1,048,576 B
    short*  Pmh    = (short*)(w + 35651584);      //  1,048,576 B
    short*  Pml    = (short*)(w + 36700160);      //  1,048,576 B
    short*  Klh    = (short*)(w + 37748736);      //    524,288 B
    short*  Kll    = (short*)(w + 38273024);      //    524,288 B
    float*  rLtab  = (float*)(w + 38797312);      //     32,768 B
    float*  rL2tab = (float*)(w + 38830080);      //     32,768 B
    double* stats  = (double*)(w + 38862848);     //      1,024 B   (~38.9 MB)

    hipMemsetAsync(stats, 0, 1024, stream);
    hipLaunchKernelGGL(k0_setup, dim3(64),   dim3(64),  0, stream,
                       log_dt, C_ri, log_A_real, A_imag, rLtab, rL2tab,
                       Qh, Ql, Pmh, Pml, Klh, Kll);
    hipLaunchKernelGGL(k_fused,  dim3(1024), dim3(256), 0, stream,
                       u, length, D, rLtab, rL2tab, Qh, Ql, Pmh, Pml, Klh, Kll, y, stats);
    hipLaunchKernelGGL(k4_final, dim3(65536), dim3(256), 0, stream,
                       u, y, cond, film_w, film_b, stats, out);
}